// Round 5
// baseline (103.412 us; speedup 1.0000x reference)
//
#include <hip/hip_runtime.h>
#include <math.h>

#define HALF 64
#define DFE  128
#define B    4096          // HALF*HALF
#define NF   8192          // 2*B
#define GRAM_BLOCKS  32
#define SAME_BLOCKS  512
#define CROSS_BLOCKS 512
#define PAIR_BLOCKS  (SAME_BLOCKS + CROSS_BLOCKS)
#define LOG2E 1.4426950408889634074

// K(u)=u+u^2+u^4+u^8+u^16, u=2^{-(d*d)}; d pre-scaled by sqrt(log2e/(4*Dm)).
// 10 full-rate f32 + 1 v_exp_f32 per pair.
__device__ __forceinline__ void kern1(float d, float& b1, float& b2, float& b3) {
    const float u  = __builtin_amdgcn_exp2f(-(d * d));
    const float u2 = u * u;
    const float u4 = u2 * u2;
    const float u8 = u4 * u4;
    b1 += (u + u2);
    b2 += (u4 + u8);
    b3  = fmaf(u8, u8, b3);                  // + u^16
}

__device__ __forceinline__ void kern2(float fi, float2 v,
                                      float2& a1, float2& a2, float2& a3) {
    kern1(fi - v.x, a1.x, a2.x, a3.x);
    kern1(fi - v.y, a1.y, a2.y, a3.y);
}

// ---------------- K1: cosine Gram (f64) -> f32 ff + f64 moment partials ----
__global__ __launch_bounds__(256) void gram_kernel(const float* __restrict__ feats,
                                                   float* __restrict__ ff,
                                                   double* __restrict__ pm,
                                                   unsigned int* __restrict__ ctr) {
    __shared__ float  xs[HALF][DFE];        // 32 KB
    __shared__ double xd[HALF][DFE + 1];    // padded: conflict-free j-reads
    __shared__ double inv[HALF];
    __shared__ double red1[256], red2[256];
    const int h   = blockIdx.x >> 4;
    const int seg = blockIdx.x & 15;
    const int tid = threadIdx.x;
    if (blockIdx.x == 0 && tid == 0) ctr[0] = 0u;   // reset done-counter each call
    const float* base = feats + h * HALF * DFE;

    for (int idx = tid; idx < HALF * DFE; idx += 256)
        xs[idx >> 7][idx & 127] = base[idx];
    __syncthreads();

    if (tid < HALF) {
        double s0 = 0, s1 = 0, s2 = 0, s3 = 0;
        for (int k = 0; k < DFE; k += 4) {
            const double v0 = xs[tid][k],     v1 = xs[tid][k + 1];
            const double v2 = xs[tid][k + 2], v3 = xs[tid][k + 3];
            s0 = fma(v0, v0, s0); s1 = fma(v1, v1, s1);
            s2 = fma(v2, v2, s2); s3 = fma(v3, v3, s3);
        }
        inv[tid] = 1.0 / fmax(sqrt((s0 + s1) + (s2 + s3)), 1e-8);
    }
    __syncthreads();

    for (int idx = tid; idx < HALF * DFE; idx += 256) {
        const int i = idx >> 7, k = idx & 127;
        xd[i][k] = (double)xs[i][k] * inv[i];
    }
    __syncthreads();

    const int p = seg * 256 + tid;
    const int i = p >> 6, j = p & 63;      // i wave-uniform, j per-lane
    double s0 = 0, s1 = 0, s2 = 0, s3 = 0;
    for (int k = 0; k < DFE; k += 4) {
        s0 = fma(xd[i][k],     xd[j][k],     s0);
        s1 = fma(xd[i][k + 1], xd[j][k + 1], s1);
        s2 = fma(xd[i][k + 2], xd[j][k + 2], s2);
        s3 = fma(xd[i][k + 3], xd[j][k + 3], s3);
    }
    const double v = (s0 + s1) + (s2 + s3);
    ff[h * B + p] = (float)v;              // f32 for the pair phase

    red1[tid] = v; red2[tid] = v * v;      // moments stay f64-accurate
    __syncthreads();
    for (int off = 128; off > 0; off >>= 1) {
        if (tid < off) { red1[tid] += red1[tid + off]; red2[tid] += red2[tid + off]; }
        __syncthreads();
    }
    if (tid == 0) {
        pm[2 * blockIdx.x]     = red1[0];
        pm[2 * blockIdx.x + 1] = red2[0];
    }
}

// ---------------- K2: pair sums + fused last-block final reduce ------------
// blocks [0,512):   same-half unordered pairs; LDS interleave (t, t+1024)
//                   so one ds_read_b64 feeds distances k and k+1024.
// blocks [512,1024): src x trgt, 8 rows x full half; interleave (t, t+2048).
__global__ __launch_bounds__(256, 4) void pair_kernel(const float* __restrict__ ff,
                                                      const double* __restrict__ pm,
                                                      double* __restrict__ partials,
                                                      unsigned int* __restrict__ ctr,
                                                      float* __restrict__ out) {
    __shared__ float2 fsI[B];      // 32 KB
    __shared__ double red[256];
    __shared__ int lastFlag;
    const int tid = threadIdx.x;
    const int bid = blockIdx.x;

    // scl from gram moment partials (uniform loads, fixed order, f64)
    double s1 = 0.0, s2 = 0.0;
    #pragma unroll
    for (int q = 0; q < GRAM_BLOCKS; ++q) { s1 += pm[2 * q]; s2 += pm[2 * q + 1]; }
    const double m1 = s1 * (1.0 / NF);
    const double m2 = s2 * (1.0 / NF);
    const double Dm = 2.0 * (m2 - m1 * m1);
    const float scl = (float)sqrt(LOG2E / (4.0 * Dm));

    float2 a1 = {0.f, 0.f}, a2 = {0.f, 0.f}, a3 = {0.f, 0.f};

    if (bid < SAME_BLOCKS) {
        const int ti = tid >> 4, tj = tid & 15;
        const int ig = bid * 16 + ti;          // global row (blocks never straddle)
        const int il = ig & 4095;
        const float* fh = ff + ((ig >> 12) << 12);
        for (int t = tid; t < B; t += 256)
            fsI[t] = make_float2(fh[t] * scl, fh[(t + 1024) & 4095] * scl);
        __syncthreads();
        const float fi = fsI[il].x;
        const int base = il + 1 + tj;
        // m=0..62: distances k=1+tj+16m (<=1008) and k+1024 per b64 read
        #pragma unroll 4
        for (int m = 0; m < 63; ++m)
            kern2(fi, fsI[(base + (m << 4)) & 4095], a1, a2, a3);
        if (tj < 15) {                         // k = 1009+tj (1009..1023) & +1024
            kern2(fi, fsI[(il + 1009 + tj) & 4095], a1, a2, a3);
        } else {                               // k = 1024, exactly once per row
            kern1(fi - fsI[il].y, a1.x, a2.x, a3.x);
        }
        if (tj == 0 && il < 2048)              // k = 2048, once per pair
            kern1(fi - fsI[il + 2048].x, a1.x, a2.x, a3.x);
    } else {
        const int bc  = bid - SAME_BLOCKS;     // 0..511
        const int row = bc * 8 + (tid >> 5);   // src row 0..4095
        const int tj  = tid & 31;
        const float* ft = ff + B;
        for (int t = tid; t < 2048; t += 256)
            fsI[t] = make_float2(ft[t] * scl, ft[t + 2048] * scl);
        __syncthreads();
        const float fi = ff[row] * scl;
        #pragma unroll 4
        for (int m = 0; m < 64; ++m)
            kern2(fi, fsI[tj + (m << 5)], a1, a2, a3);
    }

    red[tid] = (((double)a1.x + (double)a1.y) + ((double)a2.x + (double)a2.y))
             + ((double)a3.x + (double)a3.y);
    __syncthreads();
    for (int off = 128; off > 0; off >>= 1) {
        if (tid < off) red[tid] += red[tid + off];
        __syncthreads();
    }
    if (tid == 0) partials[bid] = red[0];
    __threadfence();                           // release partial before counting
    if (tid == 0) {
        const unsigned int old = atomicAdd(ctr, 1u);
        lastFlag = (old == PAIR_BLOCKS - 1);
    }
    __syncthreads();

    if (lastFlag) {                            // last block: deterministic final
        __threadfence();                       // acquire all partials
        double a = 0.0, b = 0.0;
        for (int i = tid; i < SAME_BLOCKS; i += 256)  a += partials[i];
        for (int i = tid; i < CROSS_BLOCKS; i += 256) b += partials[SAME_BLOCKS + i];
        double* sc = (double*)fsI;             // reuse LDS as scratch
        sc[tid] = a; sc[256 + tid] = b;
        __syncthreads();
        for (int off = 128; off > 0; off >>= 1) {
            if (tid < off) { sc[tid] += sc[tid + off]; sc[256 + tid] += sc[256 + tid + off]; }
            __syncthreads();
        }
        if (tid == 0) {
            const double S_same  = 2.0 * sc[0];     // unordered -> ordered
            const double S_cross = 2.0 * sc[256];   // one direction -> both
            const double bb = (double)B;
            const double loss = S_same / (bb * (bb - 1.0))
                              - S_cross / (bb * bb)
                              + 2.0 / (bb - 1.0);
            out[0] = (float)loss;
        }
    }
}

extern "C" void kernel_launch(void* const* d_in, const int* in_sizes, int n_in,
                              void* d_out, int out_size, void* d_ws, size_t ws_size,
                              hipStream_t stream) {
    const float* feats = (const float*)d_in[0];
    float* out = (float*)d_out;
    double* ws = (double*)d_ws;

    double*       pm       = ws;                         // 64 doubles
    double*       partials = ws + 64;                    // 1024 doubles
    unsigned int* ctr      = (unsigned int*)(ws + 64 + 1024);   // 1 uint (8B slot)
    float*        ff       = (float*)(ws + 64 + 1024 + 1);      // 8192 floats

    gram_kernel<<<GRAM_BLOCKS, 256, 0, stream>>>(feats, ff, pm, ctr);
    pair_kernel<<<PAIR_BLOCKS, 256, 0, stream>>>(ff, pm, partials, ctr, out);
}

// Round 7
// 27.805 us; speedup vs baseline: 3.7192x; 3.7192x over previous
//
#include <hip/hip_runtime.h>
#include <math.h>

typedef float v2f __attribute__((ext_vector_type(2)));

#define HALF 64
#define DFE  128
#define B    4096          // HALF*HALF
#define NF   8192          // 2*B
#define GRAM_BLOCKS  32
#define SAME_BLOCKS  512   // 16 rows each (both halves)
#define CROSS_BLOCKS 512   // 8 src rows each x full trgt half
#define PAIR_BLOCKS  (SAME_BLOCKS + CROSS_BLOCKS)
#define LOG2E 1.4426950408889634074

// K(u)=u+u^2+u^4+u^8+u^16, u=2^{-(d*d)}; d pre-scaled by sqrt(log2e/(4*Dm)).
// Packed f32 (v_pk_*): 10 pk-ops + 2 v_exp_f32 per TWO pairs.
// d=1e18 sentinel => m=1e36 => exp2(-1e36)=0 exactly => pair contributes 0.
__device__ __forceinline__ void kern_d(v2f d, v2f& a1, v2f& a2, v2f& a3) {
    const v2f m = d * d;
    v2f u;
    u.x = __builtin_amdgcn_exp2f(-m.x);
    u.y = __builtin_amdgcn_exp2f(-m.y);
    const v2f u2 = u * u;
    const v2f u4 = u2 * u2;
    const v2f u8 = u4 * u4;
    a1 += u + u2;
    a2 += u4 + u8;
    a3 += u8 * u8;     // + u^16
}

// ---------------- K1: cosine Gram (f64) -> f32 ff + f64 moment partials ----
__global__ __launch_bounds__(256) void gram_kernel(const float* __restrict__ feats,
                                                   float* __restrict__ ff,
                                                   double* __restrict__ pm) {
    __shared__ float  xs[HALF][DFE];        // 32 KB
    __shared__ double xd[HALF][DFE + 1];    // padded: conflict-free j-reads
    __shared__ double inv[HALF];
    __shared__ double red1[256], red2[256];
    const int h   = blockIdx.x >> 4;
    const int seg = blockIdx.x & 15;
    const int tid = threadIdx.x;
    const float* base = feats + h * HALF * DFE;

    for (int idx = tid; idx < HALF * DFE; idx += 256)
        xs[idx >> 7][idx & 127] = base[idx];
    __syncthreads();

    if (tid < HALF) {
        double s0 = 0, s1 = 0, s2 = 0, s3 = 0;
        for (int k = 0; k < DFE; k += 4) {
            const double v0 = xs[tid][k],     v1 = xs[tid][k + 1];
            const double v2 = xs[tid][k + 2], v3 = xs[tid][k + 3];
            s0 = fma(v0, v0, s0); s1 = fma(v1, v1, s1);
            s2 = fma(v2, v2, s2); s3 = fma(v3, v3, s3);
        }
        inv[tid] = 1.0 / fmax(sqrt((s0 + s1) + (s2 + s3)), 1e-8);
    }
    __syncthreads();

    for (int idx = tid; idx < HALF * DFE; idx += 256) {
        const int i = idx >> 7, k = idx & 127;
        xd[i][k] = (double)xs[i][k] * inv[i];
    }
    __syncthreads();

    const int p = seg * 256 + tid;
    const int i = p >> 6, j = p & 63;      // i wave-uniform, j per-lane
    double s0 = 0, s1 = 0, s2 = 0, s3 = 0;
    for (int k = 0; k < DFE; k += 4) {
        s0 = fma(xd[i][k],     xd[j][k],     s0);
        s1 = fma(xd[i][k + 1], xd[j][k + 1], s1);
        s2 = fma(xd[i][k + 2], xd[j][k + 2], s2);
        s3 = fma(xd[i][k + 3], xd[j][k + 3], s3);
    }
    const double v = (s0 + s1) + (s2 + s3);
    ff[h * B + p] = (float)v;              // f32 for the pair phase

    red1[tid] = v; red2[tid] = v * v;      // moments stay f64-accurate
    __syncthreads();
    for (int off = 128; off > 0; off >>= 1) {
        if (tid < off) { red1[tid] += red1[tid + off]; red2[tid] += red2[tid + off]; }
        __syncthreads();
    }
    if (tid == 0) {
        pm[2 * blockIdx.x]     = red1[0];
        pm[2 * blockIdx.x + 1] = red2[0];
    }
}

// ---------------- K2: pair sums, register-tiled rows -----------------------
// Same-half blocks: rows r0..r0+15 in VGPRs; uniform j-window c in [16,2063],
//   gap g = c - rho. Main covers g in [16-rho, 2047] (tail threads exclude
//   g >= 2048 via rho < c-2047). Edge covers g in [1, 15-rho] + half-counted
//   g = 2048 (rows in first half only).
// Cross blocks: 8 src rows in VGPRs x all 4096 trgt values, no predicates.
// NOTE (R5 lesson): NO threadfence/atomic fusion here — device-scope release
// per block serialized on L2 writeback (94us). Separate final kernel is ~3us.
__global__ __launch_bounds__(256, 4) void pair_kernel(const float* __restrict__ ff,
                                                      const double* __restrict__ pm,
                                                      double* __restrict__ partials) {
    __shared__ float  fs[B];       // 16 KB: one half of f, pre-scaled
    __shared__ double red[256];
    const int tid = threadIdx.x;
    const int bid = blockIdx.x;

    // scl from gram moment partials (uniform loads, fixed order, f64)
    double s1 = 0.0, s2 = 0.0;
    #pragma unroll
    for (int q = 0; q < GRAM_BLOCKS; ++q) { s1 += pm[2 * q]; s2 += pm[2 * q + 1]; }
    const double m1 = s1 * (1.0 / NF);
    const double m2 = s2 * (1.0 / NF);
    const double Dm = 2.0 * (m2 - m1 * m1);
    const float scl = (float)sqrt(LOG2E / (4.0 * Dm));

    v2f a1 = {0.f, 0.f}, a2 = {0.f, 0.f}, a3 = {0.f, 0.f};

    if (bid < SAME_BLOCKS) {
        const int r0g = bid * 16;              // global row base
        const int r0l = r0g & 4095;            // local row base (mult of 16)
        const float* fh = ff + ((r0g >> 12) << 12);
        const float4* fh4 = (const float4*)fh;
        float4* fs4 = (float4*)fs;
        #pragma unroll
        for (int k = 0; k < 4; ++k) {
            float4 v = fh4[tid + 256 * k];
            v.x *= scl; v.y *= scl; v.z *= scl; v.w *= scl;
            fs4[tid + 256 * k] = v;
        }
        __syncthreads();

        v2f fi[8];                             // 16 rows in registers
        #pragma unroll
        for (int q = 0; q < 8; ++q) {
            fi[q].x = fs[r0l + 2 * q];
            fi[q].y = fs[r0l + 2 * q + 1];
        }

        const int c0 = 16 + (tid << 3);        // this thread's 8 c-values
        const int j0 = (r0l + c0) & 4095;      // mult of 8 -> aligned b128
        float vj[8];
        *(float4*)&vj[0] = *(const float4*)&fs[j0];
        *(float4*)&vj[4] = *(const float4*)&fs[j0 + 4];

        if (c0 <= 2039) {                      // clean: g = c-rho <= 2046 always
            #pragma unroll
            for (int e = 0; e < 8; ++e) {
                v2f vv; vv.x = vj[e]; vv.y = vj[e];
                #pragma unroll
                for (int q = 0; q < 8; ++q)
                    kern_d(fi[q] - vv, a1, a2, a3);
            }
        } else {                               // tail: exclude g >= 2048 only
            #pragma unroll
            for (int e = 0; e < 8; ++e) {
                const int ov = c0 + e - 2047;  // rows rho < ov have g >= 2048
                v2f vv; vv.x = vj[e]; vv.y = vj[e];
                #pragma unroll
                for (int q = 0; q < 8; ++q) {
                    v2f d = fi[q] - vv;
                    if (2 * q     < ov) d.x = 1e18f;
                    if (2 * q + 1 < ov) d.y = 1e18f;
                    kern_d(d, a1, a2, a3);
                }
            }
        }

        {   // edge: triangle gaps g in [1, 15-rho]  +  half-counted gap 2048
            const int rho = tid >> 4;
            const int g   = (tid & 15) + 1;
            v2f d;
            d.x = (g + rho <= 15)
                ? (fs[r0l + rho] - fs[(r0l + rho + g) & 4095]) : 1e18f;
            d.y = (tid < 16 && (r0l + tid) < 2048)
                ? (fs[r0l + tid] - fs[(r0l + tid + 2048) & 4095]) : 1e18f;
            kern_d(d, a1, a2, a3);
        }
    } else {
        const int bc  = bid - SAME_BLOCKS;     // 0..511
        const int r0c = bc * 8;                // src rows r0c..r0c+7
        const float* ft = ff + B;
        const float4* ft4 = (const float4*)ft;
        float4* fs4 = (float4*)fs;
        #pragma unroll
        for (int k = 0; k < 4; ++k) {
            float4 v = ft4[tid + 256 * k];
            v.x *= scl; v.y *= scl; v.z *= scl; v.w *= scl;
            fs4[tid + 256 * k] = v;
        }
        __syncthreads();

        v2f fi[4];                             // 8 src rows in registers
        #pragma unroll
        for (int q = 0; q < 4; ++q) {
            fi[q].x = ff[r0c + 2 * q]     * scl;
            fi[q].y = ff[r0c + 2 * q + 1] * scl;
        }

        const int c0 = tid << 4;               // 16 contiguous trgt values
        float vj[16];
        #pragma unroll
        for (int k = 0; k < 4; ++k)
            *(float4*)&vj[4 * k] = *(const float4*)&fs[c0 + 4 * k];

        #pragma unroll
        for (int e = 0; e < 16; ++e) {
            v2f vv; vv.x = vj[e]; vv.y = vj[e];
            #pragma unroll
            for (int q = 0; q < 4; ++q)
                kern_d(fi[q] - vv, a1, a2, a3);
        }
    }

    red[tid] = ((double)a1.x + (double)a1.y)
             + ((double)a2.x + (double)a2.y)
             + ((double)a3.x + (double)a3.y);
    __syncthreads();
    for (int off = 128; off > 0; off >>= 1) {
        if (tid < off) red[tid] += red[tid + off];
        __syncthreads();
    }
    if (tid == 0) partials[bid] = red[0];
}

// ---------------- K3: deterministic final reduce + loss --------------------
__global__ __launch_bounds__(256) void final_kernel(const double* __restrict__ partials,
                                                    float* __restrict__ out) {
    __shared__ double rs[256], rc[256];
    const int tid = threadIdx.x;
    double a = 0.0, b = 0.0;
    for (int i = tid; i < SAME_BLOCKS; i += 256)  a += partials[i];
    for (int i = tid; i < CROSS_BLOCKS; i += 256) b += partials[SAME_BLOCKS + i];
    rs[tid] = a; rc[tid] = b;
    __syncthreads();
    for (int off = 128; off > 0; off >>= 1) {
        if (tid < off) { rs[tid] += rs[tid + off]; rc[tid] += rc[tid + off]; }
        __syncthreads();
    }
    if (tid == 0) {
        const double S_same  = 2.0 * rs[0];   // unordered -> ordered
        const double S_cross = 2.0 * rc[0];   // one direction -> both
        const double bb = (double)B;
        const double loss = S_same / (bb * (bb - 1.0))
                          - S_cross / (bb * bb)
                          + 2.0 / (bb - 1.0);
        out[0] = (float)loss;
    }
}

extern "C" void kernel_launch(void* const* d_in, const int* in_sizes, int n_in,
                              void* d_out, int out_size, void* d_ws, size_t ws_size,
                              hipStream_t stream) {
    const float* feats = (const float*)d_in[0];
    float* out = (float*)d_out;
    double* ws = (double*)d_ws;

    double* pm       = ws;                         // 64 doubles
    double* partials = ws + 64;                    // 1024 doubles
    float*  ff       = (float*)(ws + 64 + 1024);   // 8192 floats

    gram_kernel <<<GRAM_BLOCKS, 256, 0, stream>>>(feats, ff, pm);
    pair_kernel <<<PAIR_BLOCKS, 256, 0, stream>>>(ff, pm, partials);
    final_kernel<<<1,           256, 0, stream>>>(partials, out);
}

// Round 8
// 23.839 us; speedup vs baseline: 4.3378x; 1.1663x over previous
//
#include <hip/hip_runtime.h>
#include <math.h>

typedef float v2f __attribute__((ext_vector_type(2)));

#define HALF 64
#define DFE  128
#define B    4096          // HALF*HALF
#define NF   8192          // 2*B
#define GRAM_BLOCKS  32
#define SAME_BLOCKS  1024  // 8 rows each (both halves)
#define CROSS_BLOCKS 1024  // 4 src rows each x full trgt half
#define PAIR_BLOCKS  (SAME_BLOCKS + CROSS_BLOCKS)
#define LOG2E 1.4426950408889634074
#define XPAD 130           // f32 row stride in gram LDS (2-mod-32 -> <=4-way banks)

// K(u)=u+u^2+u^4+u^8+u^16, u=2^{-(d*d)}; d pre-scaled by sqrt(log2e/(4*Dm)).
// Packed f32: ~10 pk-ops + 2 v_exp_f32 per TWO pairs.
// d=1e18 sentinel => exp2(-1e36)=0 exactly => pair contributes 0.
__device__ __forceinline__ void kern_d(v2f d, v2f& a1, v2f& a2, v2f& a3) {
    const v2f m = d * d;
    v2f u;
    u.x = __builtin_amdgcn_exp2f(-m.x);
    u.y = __builtin_amdgcn_exp2f(-m.y);
    const v2f u2 = u * u;
    const v2f u4 = u2 * u2;
    const v2f u8 = u4 * u4;
    a1 += u + u2;
    a2 += u4 + u8;
    a3 += u8 * u8;     // + u^16
}

// ---------------- K1: cosine Gram (f64 dots of f32 rows) -------------------
// f_ij = R_ij * inv_i * inv_j, inv = 1/max(sqrt(R_ii),1e-8). No f64 LDS copy.
__global__ __launch_bounds__(256) void gram_kernel(const float* __restrict__ feats,
                                                   float* __restrict__ ff,
                                                   double* __restrict__ pm) {
    __shared__ float  xs[HALF * XPAD];   // ~33 KB padded f32
    __shared__ double nrmp[256];
    __shared__ double inv[HALF];
    __shared__ double wred[8];
    const int h   = blockIdx.x >> 4;
    const int seg = blockIdx.x & 15;
    const int tid = threadIdx.x;
    const float* base = feats + h * HALF * DFE;

    // stage: float4 global loads -> float2 LDS writes (stride-130 rows)
    #pragma unroll
    for (int m = 0; m < 8; ++m) {
        const int idx = tid + 256 * m;            // 2048 float4s
        const int r = idx >> 5, s = (idx & 31) << 2;
        const float4 v = *(const float4*)(base + r * DFE + s);
        *(float2*)&xs[r * XPAD + s]     = make_float2(v.x, v.y);
        *(float2*)&xs[r * XPAD + s + 2] = make_float2(v.z, v.w);
    }
    __syncthreads();

    // norms: 4 threads per row (32 elems each), f64 partials
    {
        const int r = tid & 63, hh = tid >> 6;
        const float* row = &xs[r * XPAD + 32 * hh];
        double s0 = 0.0, s1 = 0.0;
        #pragma unroll
        for (int k = 0; k < 32; k += 2) {
            const float2 v = *(const float2*)&row[k];
            s0 = fma((double)v.x, (double)v.x, s0);
            s1 = fma((double)v.y, (double)v.y, s1);
        }
        nrmp[hh * 64 + r] = s0 + s1;
    }
    __syncthreads();
    if (tid < HALF) {
        const double s = (nrmp[tid] + nrmp[64 + tid]) + (nrmp[128 + tid] + nrmp[192 + tid]);
        inv[tid] = 1.0 / fmax(sqrt(s), 1e-8);
    }
    __syncthreads();

    // dot: one output per thread; i wave-uniform (broadcast reads), j per-lane
    const int p = seg * 256 + tid;
    const int i = p >> 6, j = p & 63;
    const float* ri = &xs[i * XPAD];
    const float* rj = &xs[j * XPAD];
    double s0 = 0.0, s1 = 0.0;
    #pragma unroll 8
    for (int k = 0; k < DFE; k += 2) {
        const float2 a = *(const float2*)&ri[k];
        const float2 b = *(const float2*)&rj[k];
        s0 = fma((double)a.x, (double)b.x, s0);
        s1 = fma((double)a.y, (double)b.y, s1);
    }
    const double v = (s0 + s1) * inv[i] * inv[j];
    ff[h * B + p] = (float)v;              // f32 for the pair phase

    // moments (f64): in-wave butterfly, then 4 wave-partials via LDS
    double r1 = v, r2 = v * v;
    #pragma unroll
    for (int msk = 1; msk < 64; msk <<= 1) {
        r1 += __shfl_xor(r1, msk);
        r2 += __shfl_xor(r2, msk);
    }
    if ((tid & 63) == 0) { wred[(tid >> 6) * 2] = r1; wred[(tid >> 6) * 2 + 1] = r2; }
    __syncthreads();
    if (tid == 0) {
        pm[2 * blockIdx.x]     = (wred[0] + wred[2]) + (wred[4] + wred[6]);
        pm[2 * blockIdx.x + 1] = (wred[1] + wred[3]) + (wred[5] + wred[7]);
    }
}

// ---------------- K2: pair sums, 2048 uniform blocks -----------------------
// Same blocks (bid<1024): 8 rows in VGPRs, uniform window c in [8,2055]
//   (NO predication in main loop); the 36 over-counted g>=2048 pairs are
//   recomputed into negative accumulators; edge adds g in [1,7-rho] (28)
//   + straddle g=2048 (8, first-half blocks only).
// Cross blocks: 4 src rows x full trgt half.
// scl computed by wave 0 (shfl butterfly over pm) OVERLAPPED with staging.
// NOTE (R5 lesson): NO threadfence/atomic fusion — device-scope release per
// block serialized on L2 writeback (94us). Separate final kernel is cheap.
__global__ __launch_bounds__(256, 8) void pair_kernel(const float* __restrict__ ff,
                                                      const double* __restrict__ pm,
                                                      double* __restrict__ partials) {
    __shared__ float  fs[B];       // 16 KB raw half
    __shared__ float  sclS;
    __shared__ double wred[4];
    const int tid = threadIdx.x;
    const int bid = blockIdx.x;
    const bool same = bid < SAME_BLOCKS;
    const int  r0g  = same ? (bid << 3) : 0;
    const float* src = same ? (ff + (r0g & 4096)) : (ff + B);

    {   // stage 16 KB (raw, scale applied at fragment load)
        const float4* s4 = (const float4*)src;
        float4* d4 = (float4*)fs;
        #pragma unroll
        for (int k = 0; k < 4; ++k) d4[tid + 256 * k] = s4[tid + 256 * k];
    }
    if (tid < 64) {   // wave 0: scl from gram moments, hidden under staging
        double s = pm[tid];
        #pragma unroll
        for (int msk = 2; msk <= 32; msk <<= 1) s += __shfl_xor(s, msk);
        const double o = __shfl_xor(s, 1);     // lane0: s=sum, o=sumsq
        if (tid == 0) {
            const double m1 = s * (1.0 / NF);
            const double m2 = o * (1.0 / NF);
            const double Dm = 2.0 * (m2 - m1 * m1);
            sclS = (float)sqrt(LOG2E / (4.0 * Dm));
        }
    }
    __syncthreads();
    const float scl = sclS;

    v2f a1 = {0.f,0.f}, a2 = {0.f,0.f}, a3 = {0.f,0.f};
    v2f n1 = {0.f,0.f}, n2 = {0.f,0.f}, n3 = {0.f,0.f};

    if (same) {
        const int r0l = r0g & 4095;            // multiple of 8
        v2f fi[4];                             // 8 rows (broadcast LDS reads)
        #pragma unroll
        for (int q = 0; q < 4; ++q) {
            fi[q].x = fs[r0l + 2 * q]     * scl;
            fi[q].y = fs[r0l + 2 * q + 1] * scl;
        }
        const int c0 = 8 + (tid << 3);         // 8 c-values, c in [8,2055]
        const int j0 = (r0l + c0) & 4095;      // 8-aligned -> aligned b128
        float vj[8];
        *(float4*)&vj[0] = *(const float4*)&fs[j0];
        *(float4*)&vj[4] = *(const float4*)&fs[j0 + 4];
        #pragma unroll
        for (int e = 0; e < 8; ++e) {          // fully uniform main loop
            v2f vv; vv.x = vj[e] * scl; vv.y = vj[e] * scl;
            #pragma unroll
            for (int q = 0; q < 4; ++q)
                kern_d(fi[q] - vv, a1, a2, a3);
        }
        if (tid < 18) {
            // subtract the 36 over-counted pairs: c=2048+m (m<8), rho<=m
            v2f d;
            #pragma unroll
            for (int hp = 0; hp < 2; ++hp) {
                const int idx = 2 * tid + hp;              // [0,36)
                const int m   = (int)((sqrtf((float)(8 * idx + 1)) - 1.0f) * 0.5f);
                const int rho = idx - ((m * (m + 1)) >> 1);
                const float dv = (fs[r0l + rho] - fs[(r0l + 2048 + m) & 4095]) * scl;
                if (hp == 0) d.x = dv; else d.y = dv;
            }
            kern_d(d, n1, n2, n3);
            // add: 28 intra-block triangle (g in [1,7-rho]) + 8 straddle g=2048
            v2f d2;
            #pragma unroll
            for (int hp = 0; hp < 2; ++hp) {
                const int idx = 2 * tid + hp;              // [0,36)
                float dv;
                if (idx < 28) {
                    const int m   = (int)((1.0f + sqrtf((float)(1 + 8 * idx))) * 0.5f);
                    const int g   = idx - ((m * (m - 1)) >> 1) + 1;
                    const int rho = m - g;
                    dv = (fs[r0l + rho] - fs[r0l + rho + g]) * scl;
                } else {
                    const int rho = idx - 28;
                    dv = (r0l < 2048)
                       ? (fs[r0l + rho] - fs[r0l + rho + 2048]) * scl : 1e18f;
                }
                if (hp == 0) d2.x = dv; else d2.y = dv;
            }
            kern_d(d2, a1, a2, a3);
        }
    } else {
        const int r0c = (bid - SAME_BLOCKS) << 2;  // 4 src rows
        v2f fi[2];
        #pragma unroll
        for (int q = 0; q < 2; ++q) {
            fi[q].x = ff[r0c + 2 * q]     * scl;
            fi[q].y = ff[r0c + 2 * q + 1] * scl;
        }
        const int c0 = tid << 4;               // 16 contiguous trgt values
        float vj[16];
        #pragma unroll
        for (int k = 0; k < 4; ++k)
            *(float4*)&vj[4 * k] = *(const float4*)&fs[c0 + 4 * k];
        #pragma unroll
        for (int e = 0; e < 16; ++e) {
            v2f vv; vv.x = vj[e] * scl; vv.y = vj[e] * scl;
            #pragma unroll
            for (int q = 0; q < 2; ++q)
                kern_d(fi[q] - vv, a1, a2, a3);
        }
    }

    // block reduce: f64 convert, in-wave butterfly, 4 wave-partials via LDS
    double t = (((double)a1.x + (double)a1.y) + ((double)a2.x + (double)a2.y)
             +  ((double)a3.x + (double)a3.y))
             - (((double)n1.x + (double)n1.y) + ((double)n2.x + (double)n2.y)
             +  ((double)n3.x + (double)n3.y));
    #pragma unroll
    for (int msk = 1; msk < 64; msk <<= 1) t += __shfl_xor(t, msk);
    if ((tid & 63) == 0) wred[tid >> 6] = t;
    __syncthreads();
    if (tid == 0) partials[bid] = (wred[0] + wred[1]) + (wred[2] + wred[3]);
}

// ---------------- K3: deterministic final reduce + loss --------------------
__global__ __launch_bounds__(256) void final_kernel(const double* __restrict__ partials,
                                                    float* __restrict__ out) {
    __shared__ double rs[256], rc[256];
    const int tid = threadIdx.x;
    double a = 0.0, b = 0.0;
    for (int i = tid; i < SAME_BLOCKS; i += 256)  a += partials[i];
    for (int i = tid; i < CROSS_BLOCKS; i += 256) b += partials[SAME_BLOCKS + i];
    rs[tid] = a; rc[tid] = b;
    __syncthreads();
    for (int off = 128; off > 0; off >>= 1) {
        if (tid < off) { rs[tid] += rs[tid + off]; rc[tid] += rc[tid + off]; }
        __syncthreads();
    }
    if (tid == 0) {
        const double S_same  = 2.0 * rs[0];   // unordered -> ordered
        const double S_cross = 2.0 * rc[0];   // one direction -> both
        const double bb = (double)B;
        const double loss = S_same / (bb * (bb - 1.0))
                          - S_cross / (bb * bb)
                          + 2.0 / (bb - 1.0);
        out[0] = (float)loss;
    }
}

extern "C" void kernel_launch(void* const* d_in, const int* in_sizes, int n_in,
                              void* d_out, int out_size, void* d_ws, size_t ws_size,
                              hipStream_t stream) {
    const float* feats = (const float*)d_in[0];
    float* out = (float*)d_out;
    double* ws = (double*)d_ws;

    double* pm       = ws;                         // 64 doubles
    double* partials = ws + 64;                    // 2048 doubles
    float*  ff       = (float*)(ws + 64 + 2048);   // 8192 floats

    gram_kernel <<<GRAM_BLOCKS, 256, 0, stream>>>(feats, ff, pm);
    pair_kernel <<<PAIR_BLOCKS, 256, 0, stream>>>(ff, pm, partials);
    final_kernel<<<1,           256, 0, stream>>>(partials, out);
}